// Round 1
// baseline (278.951 us; speedup 1.0000x reference)
//
#include <hip/hip_runtime.h>
#include <math.h>

#define EPS 1e-12f

// Problem constants (from reference setup_inputs)
constexpr int B = 32768;
constexpr int C = 1000;
constexpr int C4 = C / 4;              // 250 float4 per row
constexpr int BLOCKS = 2048;
constexpr int THREADS = 256;
constexpr int WAVES_PER_BLOCK = THREADS / 64;          // 4
constexpr int TOTAL_WAVES = BLOCKS * WAVES_PER_BLOCK;  // 8192 -> 4 rows/wave

// Per-element update: o = sigmoid(x); lp = log(o+eps); ln = log(1-o+eps);
// base -= ln; gain = lp - ln; if label==1: {pos += max(gain,0); best = max(best,gain)}
__device__ __forceinline__ void elem_update(float x, float m,
                                            float& base, float& pos, float& best) {
    float o  = 1.0f / (1.0f + __expf(-x));
    float lp = __logf(o + EPS);
    float ln = __logf(1.0f - o + EPS);
    base -= ln;
    float g = lp - ln;
    if (m == 1.0f) {
        if (g > 0.0f) pos += g;
        best = fmaxf(best, g);
    }
}

__global__ __launch_bounds__(THREADS)
void row_loss_kernel(const float* __restrict__ out_logits,
                     const float* __restrict__ labels,
                     float* __restrict__ partial) {
    const int wave_in_block = threadIdx.x >> 6;
    const int lane          = threadIdx.x & 63;
    const int gwave         = blockIdx.x * WAVES_PER_BLOCK + wave_in_block;

    float acc = 0.0f;  // sum of per_sample for this wave's rows (lane 0 only)

    for (int row = gwave; row < B; row += TOTAL_WAVES) {
        const float4* o4 = reinterpret_cast<const float4*>(out_logits + (size_t)row * C);
        const float4* m4 = reinterpret_cast<const float4*>(labels     + (size_t)row * C);

        float base = 0.0f, pos = 0.0f, best = -INFINITY;

        for (int k = lane; k < C4; k += 64) {
            float4 x = o4[k];
            float4 m = m4[k];
            elem_update(x.x, m.x, base, pos, best);
            elem_update(x.y, m.y, base, pos, best);
            elem_update(x.z, m.z, base, pos, best);
            elem_update(x.w, m.w, base, pos, best);
        }

        // wave-level reduction (64 lanes)
        #pragma unroll
        for (int off = 32; off > 0; off >>= 1) {
            base += __shfl_down(base, off, 64);
            pos  += __shfl_down(pos,  off, 64);
            best  = fmaxf(best, __shfl_down(best, off, 64));
        }

        if (lane == 0) {
            // any_pos <=> pos > 0 (sum of strictly positive gains, no cancellation)
            float max_gain = (pos > 0.0f) ? pos : best;
            acc += base - max_gain;
        }
    }

    __shared__ float s[WAVES_PER_BLOCK];
    if (lane == 0) s[wave_in_block] = acc;
    __syncthreads();
    if (threadIdx.x == 0) {
        float t = 0.0f;
        #pragma unroll
        for (int i = 0; i < WAVES_PER_BLOCK; ++i) t += s[i];
        partial[blockIdx.x] = t;
    }
}

__global__ __launch_bounds__(256)
void finalize_kernel(const float* __restrict__ partial, float* __restrict__ out) {
    // 2048 partials -> scalar mean; double accumulation for safety
    double t = 0.0;
    for (int i = threadIdx.x; i < BLOCKS; i += 256) t += (double)partial[i];

    #pragma unroll
    for (int off = 32; off > 0; off >>= 1)
        t += __shfl_down(t, off, 64);

    __shared__ double s[4];
    const int lane = threadIdx.x & 63;
    const int w    = threadIdx.x >> 6;
    if (lane == 0) s[w] = t;
    __syncthreads();
    if (threadIdx.x == 0) {
        double r = s[0] + s[1] + s[2] + s[3];
        out[0] = (float)(r / (double)B);
    }
}

extern "C" void kernel_launch(void* const* d_in, const int* in_sizes, int n_in,
                              void* d_out, int out_size, void* d_ws, size_t ws_size,
                              hipStream_t stream) {
    const float* out_logits = (const float*)d_in[0];
    const float* labels     = (const float*)d_in[1];
    float* out              = (float*)d_out;
    float* partial          = (float*)d_ws;  // BLOCKS floats = 8 KiB

    row_loss_kernel<<<BLOCKS, THREADS, 0, stream>>>(out_logits, labels, partial);
    finalize_kernel<<<1, 256, 0, stream>>>(partial, out);
}

// Round 2
// 271.759 us; speedup vs baseline: 1.0265x; 1.0265x over previous
//
#include <hip/hip_runtime.h>
#include <math.h>

// Reference math reduction (EPS=1e-12 is negligible at fp32 scale):
//   o = sigmoid(x)
//   log(o+eps)   ~= -softplus(-x)
//   log(1-o+eps) ~= -softplus(x)
//   gain = log(o)-log(1-o) = x            (the logit, exactly)
//   base = sum_j softplus(x_j)
//   pos  = sum_{m=1 & x>0} x ; best = max_{m=1} x
//   per_sample = base - (pos>0 ? pos : best)

constexpr int B = 32768;
constexpr int C = 1000;
constexpr int C4 = C / 4;              // 250 float4 per row
constexpr int BLOCKS = 2048;
constexpr int THREADS = 256;
constexpr int WAVES_PER_BLOCK = THREADS / 64;          // 4
constexpr int TOTAL_WAVES = BLOCKS * WAVES_PER_BLOCK;  // 8192 -> 4 rows/wave
constexpr int TAIL_LANES = C4 - 192;                   // 58: lanes with a 4th chunk

__device__ __forceinline__ void elem_update(float x, float m,
                                            float& base, float& pos, float& best) {
    // softplus(x) = max(x,0) + log(1 + exp(-|x|))  (stable; x=-inf -> 0)
    float e  = __expf(-fabsf(x));
    float xp = fmaxf(x, 0.0f);
    base += xp + __logf(1.0f + e);
    pos  += m * xp;                      // m in {0,1}; only x>0 contributes
    if (m != 0.0f) best = fmaxf(best, x);
}

__device__ __forceinline__ void vec_update(float4 x, float4 m,
                                           float& base, float& pos, float& best) {
    elem_update(x.x, m.x, base, pos, best);
    elem_update(x.y, m.y, base, pos, best);
    elem_update(x.z, m.z, base, pos, best);
    elem_update(x.w, m.w, base, pos, best);
}

__global__ __launch_bounds__(THREADS)
void row_loss_kernel(const float* __restrict__ X,
                     const float* __restrict__ M,
                     float* __restrict__ partial) {
    const int wave_in_block = threadIdx.x >> 6;
    const int lane          = threadIdx.x & 63;
    const int gwave         = blockIdx.x * WAVES_PER_BLOCK + wave_in_block;

    float acc = 0.0f;  // lane-0-valid after reduction

    for (int row = gwave; row < B; row += TOTAL_WAVES) {
        const float4* x4 = reinterpret_cast<const float4*>(X + (size_t)row * C);
        const float4* m4 = reinterpret_cast<const float4*>(M + (size_t)row * C);

        // Issue all loads up front (8 float4 in flight per lane).
        float4 xa = x4[lane];
        float4 xb = x4[lane + 64];
        float4 xc = x4[lane + 128];
        float4 ma = m4[lane];
        float4 mb = m4[lane + 64];
        float4 mc = m4[lane + 128];
        float4 xd = make_float4(-INFINITY, -INFINITY, -INFINITY, -INFINITY);
        float4 md = make_float4(0.0f, 0.0f, 0.0f, 0.0f);
        if (lane < TAIL_LANES) {
            xd = x4[lane + 192];
            md = m4[lane + 192];
        }

        // Independent accumulator sets for ILP.
        float b0 = 0.f, b1 = 0.f, b2 = 0.f, b3 = 0.f;
        float p0 = 0.f, p1 = 0.f, p2 = 0.f, p3 = 0.f;
        float s0 = -INFINITY, s1 = -INFINITY, s2 = -INFINITY, s3 = -INFINITY;

        vec_update(xa, ma, b0, p0, s0);
        vec_update(xb, mb, b1, p1, s1);
        vec_update(xc, mc, b2, p2, s2);
        vec_update(xd, md, b3, p3, s3);

        float base = (b0 + b1) + (b2 + b3);
        float pos  = (p0 + p1) + (p2 + p3);
        float best = fmaxf(fmaxf(s0, s1), fmaxf(s2, s3));

        // wave-level reduction (64 lanes)
        #pragma unroll
        for (int off = 32; off > 0; off >>= 1) {
            base += __shfl_down(base, off, 64);
            pos  += __shfl_down(pos,  off, 64);
            best  = fmaxf(best, __shfl_down(best, off, 64));
        }

        if (lane == 0) {
            float max_gain = (pos > 0.0f) ? pos : best;
            acc += base - max_gain;
        }
    }

    __shared__ float s[WAVES_PER_BLOCK];
    if (lane == 0) s[wave_in_block] = acc;
    __syncthreads();
    if (threadIdx.x == 0) {
        float t = 0.0f;
        #pragma unroll
        for (int i = 0; i < WAVES_PER_BLOCK; ++i) t += s[i];
        partial[blockIdx.x] = t;
    }
}

__global__ __launch_bounds__(256)
void finalize_kernel(const float* __restrict__ partial, float* __restrict__ out) {
    double t = 0.0;
    for (int i = threadIdx.x; i < BLOCKS; i += 256) t += (double)partial[i];

    #pragma unroll
    for (int off = 32; off > 0; off >>= 1)
        t += __shfl_down(t, off, 64);

    __shared__ double s[4];
    const int lane = threadIdx.x & 63;
    const int w    = threadIdx.x >> 6;
    if (lane == 0) s[w] = t;
    __syncthreads();
    if (threadIdx.x == 0) {
        double r = s[0] + s[1] + s[2] + s[3];
        out[0] = (float)(r / (double)B);
    }
}

extern "C" void kernel_launch(void* const* d_in, const int* in_sizes, int n_in,
                              void* d_out, int out_size, void* d_ws, size_t ws_size,
                              hipStream_t stream) {
    const float* X   = (const float*)d_in[0];
    const float* M   = (const float*)d_in[1];
    float* out       = (float*)d_out;
    float* partial   = (float*)d_ws;  // BLOCKS floats = 8 KiB

    row_loss_kernel<<<BLOCKS, THREADS, 0, stream>>>(X, M, partial);
    finalize_kernel<<<1, 256, 0, stream>>>(partial, out);
}